// Round 3
// baseline (540.013 us; speedup 1.0000x reference)
//
#include <hip/hip_runtime.h>
#include <hip/hip_bf16.h>
#include <stdint.h>

typedef __hip_bfloat16 bf16;
typedef __attribute__((ext_vector_type(4))) float f32x4;
typedef __attribute__((ext_vector_type(8))) short s16x8;
typedef __attribute__((ext_vector_type(4))) short s16x4;

#define DEV static __device__ __forceinline__

DEV short f2bf(float f) {
  bf16 h = __float2bfloat16(f);
  short s;
  __builtin_memcpy(&s, &h, 2);
  return s;
}
DEV float bf2f(short s) {
  bf16 h;
  __builtin_memcpy(&h, &s, 2);
  return __bfloat162float(h);
}

// ------------- transpose + f32->bf16 convert: W[K][N] -> Wt[N][K] ----------
__global__ __launch_bounds__(256) void transpose_cvt(
    const float* __restrict__ W, bf16* __restrict__ Wt, int K, int N)
{
  __shared__ float tile[32][33];
  const int n0 = blockIdx.x << 5;
  const int k0 = blockIdx.y << 5;
  const int tx = threadIdx.x & 31, ty = threadIdx.x >> 5;
#pragma unroll
  for (int i = 0; i < 4; ++i)
    tile[ty + i * 8][tx] = W[(size_t)(k0 + ty + i * 8) * N + n0 + tx];
  __syncthreads();
#pragma unroll
  for (int i = 0; i < 4; ++i)
    Wt[(size_t)(n0 + ty + i * 8) * K + k0 + tx] = __float2bfloat16(tile[tx][ty + i * 8]);
}

// ------------- layernorm (f32 in, bf16 out), D = 1024 ---------------------
__global__ __launch_bounds__(256) void ln_bf16(
    const float* __restrict__ x, const float* __restrict__ g,
    const float* __restrict__ be, bf16* __restrict__ out)
{
  const int t = threadIdx.x;
  const size_t row = blockIdx.x;
  const float4 v = ((const float4*)(x + row * 1024))[t];
  float s = v.x + v.y + v.z + v.w;
  float ss = v.x * v.x + v.y * v.y + v.z * v.z + v.w * v.w;
#pragma unroll
  for (int off = 32; off > 0; off >>= 1) {
    s += __shfl_down(s, off);
    ss += __shfl_down(ss, off);
  }
  __shared__ float sh[8];
  const int wave = t >> 6, lane = t & 63;
  if (!lane) { sh[wave] = s; sh[4 + wave] = ss; }
  __syncthreads();
  s = sh[0] + sh[1] + sh[2] + sh[3];
  ss = sh[4] + sh[5] + sh[6] + sh[7];
  const float mean = s * (1.f / 1024.f);
  const float rstd = rsqrtf(ss * (1.f / 1024.f) - mean * mean + 1e-5f);
  const float4 gv = ((const float4*)g)[t];
  const float4 bv = ((const float4*)be)[t];
  s16x4 o;
  o[0] = f2bf((v.x - mean) * rstd * gv.x + bv.x);
  o[1] = f2bf((v.y - mean) * rstd * gv.y + bv.y);
  o[2] = f2bf((v.z - mean) * rstd * gv.z + bv.z);
  o[3] = f2bf((v.w - mean) * rstd * gv.w + bv.w);
  ((s16x4*)(out + row * 1024))[t] = o;
}

// ------------- residual add + layernorm ------------------------------------
__global__ __launch_bounds__(256) void add_ln_bf16(
    const float* __restrict__ a, const float* __restrict__ x,
    const float* __restrict__ g, const float* __restrict__ be,
    bf16* __restrict__ xres, bf16* __restrict__ xnorm)
{
  const int t = threadIdx.x;
  const size_t row = blockIdx.x;
  const float4 av = ((const float4*)(a + row * 1024))[t];
  const float4 xv = ((const float4*)(x + row * 1024))[t];
  float4 v;
  v.x = av.x + xv.x; v.y = av.y + xv.y; v.z = av.z + xv.z; v.w = av.w + xv.w;
  float s = v.x + v.y + v.z + v.w;
  float ss = v.x * v.x + v.y * v.y + v.z * v.z + v.w * v.w;
#pragma unroll
  for (int off = 32; off > 0; off >>= 1) {
    s += __shfl_down(s, off);
    ss += __shfl_down(ss, off);
  }
  __shared__ float sh[8];
  const int wave = t >> 6, lane = t & 63;
  if (!lane) { sh[wave] = s; sh[4 + wave] = ss; }
  __syncthreads();
  s = sh[0] + sh[1] + sh[2] + sh[3];
  ss = sh[4] + sh[5] + sh[6] + sh[7];
  const float mean = s * (1.f / 1024.f);
  const float rstd = rsqrtf(ss * (1.f / 1024.f) - mean * mean + 1e-5f);
  const float4 gv = ((const float4*)g)[t];
  const float4 bv = ((const float4*)be)[t];
  s16x4 r, o;
  r[0] = f2bf(v.x); r[1] = f2bf(v.y); r[2] = f2bf(v.z); r[3] = f2bf(v.w);
  o[0] = f2bf((v.x - mean) * rstd * gv.x + bv.x);
  o[1] = f2bf((v.y - mean) * rstd * gv.y + bv.y);
  o[2] = f2bf((v.z - mean) * rstd * gv.z + bv.z);
  o[3] = f2bf((v.w - mean) * rstd * gv.w + bv.w);
  ((s16x4*)(xres + row * 1024))[t] = r;
  ((s16x4*)(xnorm + row * 1024))[t] = o;
}

// ------------- GEMM: C[M][N] = A[M][K] @ Bt[N][K]^T, bf16 MFMA -------------
// EPI 0: C bf16 plain. EPI 1: bf16 relu(C + bias). EPI 2: f32 C + bias + add.
template <int EPI>
__global__ __launch_bounds__(256) void gemm_bt(
    const bf16* __restrict__ A, const bf16* __restrict__ Bt,
    void* __restrict__ C, const float* __restrict__ bias,
    const bf16* __restrict__ add_bf16, int M, int N, int K)
{
  __shared__ bf16 sA[128 * 32];
  __shared__ bf16 sB[128 * 32];
  const int tid = threadIdx.x;
  const int wave = tid >> 6, lane = tid & 63;
  const int fr = lane & 15, fg = lane >> 4;
  const int wr = wave >> 1, wc = wave & 1;
  const int nbx = N >> 7;
  const int brow = (blockIdx.x / nbx) << 7;
  const int bcol = (blockIdx.x % nbx) << 7;

  f32x4 acc[4][4] = {};

  const int c0 = wave * 64 + lane;   // staging chunk (16B) index, round 0
  const int c1 = c0 + 256;           // round 1
  const size_t ga0 = (size_t)(brow + (c0 >> 2)) * K + (c0 & 3) * 8;
  const size_t ga1 = (size_t)(brow + (c1 >> 2)) * K + (c1 & 3) * 8;
  const size_t gb0 = (size_t)(bcol + (c0 >> 2)) * K + (c0 & 3) * 8;
  const size_t gb1 = (size_t)(bcol + (c1 >> 2)) * K + (c1 & 3) * 8;
  bf16* sA0 = sA + (size_t)(wave * 64) * 8;
  bf16* sA1 = sA0 + 256 * 8;
  bf16* sB0 = sB + (size_t)(wave * 64) * 8;
  bf16* sB1 = sB0 + 256 * 8;

  for (int kt = 0; kt < K; kt += 32) {
    __builtin_amdgcn_global_load_lds(
        (const __attribute__((address_space(1))) uint32_t*)(A + ga0 + kt),
        (__attribute__((address_space(3))) uint32_t*)sA0, 16, 0, 0);
    __builtin_amdgcn_global_load_lds(
        (const __attribute__((address_space(1))) uint32_t*)(A + ga1 + kt),
        (__attribute__((address_space(3))) uint32_t*)sA1, 16, 0, 0);
    __builtin_amdgcn_global_load_lds(
        (const __attribute__((address_space(1))) uint32_t*)(Bt + gb0 + kt),
        (__attribute__((address_space(3))) uint32_t*)sB0, 16, 0, 0);
    __builtin_amdgcn_global_load_lds(
        (const __attribute__((address_space(1))) uint32_t*)(Bt + gb1 + kt),
        (__attribute__((address_space(3))) uint32_t*)sB1, 16, 0, 0);
    __syncthreads();

    s16x8 af[4], bfr[4];
#pragma unroll
    for (int m = 0; m < 4; ++m)
      af[m] = *(const s16x8*)(sA + ((wr * 64 + m * 16 + fr) * 32 + fg * 8));
#pragma unroll
    for (int n = 0; n < 4; ++n)
      bfr[n] = *(const s16x8*)(sB + ((wc * 64 + n * 16 + fr) * 32 + fg * 8));
#pragma unroll
    for (int m = 0; m < 4; ++m)
#pragma unroll
      for (int n = 0; n < 4; ++n)
        acc[m][n] = __builtin_amdgcn_mfma_f32_16x16x32_bf16(af[m], bfr[n], acc[m][n], 0, 0, 0);
    __syncthreads();
  }

  const int crow = brow + wr * 64;
  const int ccol = bcol + wc * 64;
#pragma unroll
  for (int m = 0; m < 4; ++m) {
#pragma unroll
    for (int n = 0; n < 4; ++n) {
      const int col = ccol + n * 16 + fr;
#pragma unroll
      for (int j = 0; j < 4; ++j) {
        const int row = crow + m * 16 + fg * 4 + j;
        float v = acc[m][n][j];
        if (EPI == 0) {
          ((bf16*)C)[(size_t)row * N + col] = __float2bfloat16(v);
        } else if (EPI == 1) {
          v += bias[col];
          v = fmaxf(v, 0.f);
          ((bf16*)C)[(size_t)row * N + col] = __float2bfloat16(v);
        } else {
          float a;
          {
            bf16 hb = add_bf16[(size_t)row * N + col];
            a = __bfloat162float(hb);
          }
          ((float*)C)[(size_t)row * N + col] = v + bias[col] + a;
        }
      }
    }
  }
}

// ------------- flash attention v3 ------------------------------------------
// QK [4096][2048] bf16 (Q cols 0..1023, K cols 1024..2047), Vt [1024][4096] bf16
// (row = h*64+d, col = b*2048+s).  Out [4096][1024] f32.
// grid (32 q-tiles of 64, 32 bh), 512 threads = 8 waves.
// Waves 0-3 handle k in [0,1024), waves 4-7 handle [1024,2048) for the SAME
// 64 q-rows (wave&3 picks the 16-row sub-tile); online-softmax states merged
// through LDS at the end. Common-path iteration has NO cross-lane reduction
// (per-lane defer-max, threshold 8).
__global__ __launch_bounds__(512, 8) void attn_fwd(
    const bf16* __restrict__ QK, const bf16* __restrict__ Vt,
    float* __restrict__ Out)
{
  const int LDK = 2048;
  const int qt = blockIdx.x;
  const int bh = blockIdx.y;
  const int b = bh >> 4, h = bh & 15;
  const int tid = threadIdx.x;
  const int wave = tid >> 6, lane = tid & 63;
  const int fr = lane & 15, fg = lane >> 4;
  const int wq = wave & 3;           // q sub-tile (16 rows)
  const int ks = wave >> 2;          // k-split half
  const int kbeg = ks * 1024;

  const short* base = (const short*)QK + (size_t)b * 2048 * LDK;
  const short* Qp = base + h * 64;
  const short* Kp = base + 1024 + h * 64;
  const short* Vp = (const short*)Vt + (size_t)h * 64 * 4096 + b * 2048;
  const int q0 = qt * 64 + wq * 16;

  // Q fragment, pre-scaled by 1/sqrt(64) = 0.125 (exact in bf16)
  s16x8 qf0 = *(const s16x8*)(Qp + (size_t)(q0 + fr) * LDK + fg * 8);
  s16x8 qf1 = *(const s16x8*)(Qp + (size_t)(q0 + fr) * LDK + 32 + fg * 8);
#pragma unroll
  for (int i = 0; i < 8; ++i) {
    qf0[i] = f2bf(bf2f(qf0[i]) * 0.125f);
    qf1[i] = f2bf(bf2f(qf1[i]) * 0.125f);
  }

  __shared__ short P_lds[8][16 * 72];   // per-wave [16 q][72] (rows 16B-aligned)
  short* Pw = P_lds[wave];

  f32x4 acc[4] = {};
  f32x4 mrow = {-1e30f, -1e30f, -1e30f, -1e30f};
  f32x4 lrow = {};   // per-lane partial; fr-reduced once at the end

  for (int kt = kbeg; kt < kbeg + 1024; kt += 64) {
    // --- QK^T for 64 k-rows: e[t] is a 16x16 tile (q rows x k cols) ---
    f32x4 e[4];
#pragma unroll
    for (int t = 0; t < 4; ++t) {
      const short* krow = Kp + (size_t)(kt + t * 16 + fr) * LDK;
      const s16x8 k0 = *(const s16x8*)(krow + fg * 8);
      const s16x8 k1 = *(const s16x8*)(krow + 32 + fg * 8);
      f32x4 z = {};
      z = __builtin_amdgcn_mfma_f32_16x16x32_bf16(qf0, k0, z, 0, 0, 0);
      z = __builtin_amdgcn_mfma_f32_16x16x32_bf16(qf1, k1, z, 0, 0, 0);
      e[t] = z;
    }

    // --- per-lane defer-max: cross-lane tree + rescale only on growth > 8 ---
    f32x4 lmx;
#pragma unroll
    for (int j = 0; j < 4; ++j)
      lmx[j] = fmaxf(fmaxf(e[0][j], e[1][j]), fmaxf(e[2][j], e[3][j]));
    const bool need = (lmx[0] > mrow[0] + 8.f) | (lmx[1] > mrow[1] + 8.f) |
                      (lmx[2] > mrow[2] + 8.f) | (lmx[3] > mrow[3] + 8.f);
    if (__any(need)) {
      f32x4 mx = lmx;
#pragma unroll
      for (int d = 1; d < 16; d <<= 1)
#pragma unroll
        for (int j = 0; j < 4; ++j) mx[j] = fmaxf(mx[j], __shfl_xor(mx[j], d));
#pragma unroll
      for (int j = 0; j < 4; ++j) {
        const float mn = fmaxf(mrow[j], mx[j]);
        const float al = __expf(mrow[j] - mn);
        lrow[j] *= al;
        mrow[j] = mn;
#pragma unroll
        for (int nn = 0; nn < 4; ++nn) acc[nn][j] *= al;
      }
    }

    // --- exp + per-lane partial row-sum ---
    f32x4 p[4];
#pragma unroll
    for (int j = 0; j < 4; ++j) {
#pragma unroll
      for (int t = 0; t < 4; ++t) p[t][j] = __expf(e[t][j] - mrow[j]);
      lrow[j] += (p[0][j] + p[1][j]) + (p[2][j] + p[3][j]);
    }

    // --- P transpose through wave-private LDS (in-order DS, no barrier) ---
#pragma unroll
    for (int t = 0; t < 4; ++t)
#pragma unroll
      for (int j = 0; j < 4; ++j)
        Pw[(fg * 4 + j) * 72 + t * 16 + fr] = f2bf(p[t][j]);
    const s16x8 pf0 = *(const s16x8*)(Pw + fr * 72 + fg * 8);
    const s16x8 pf1 = *(const s16x8*)(Pw + fr * 72 + 32 + fg * 8);

    // --- PV: V rows contiguous thanks to Vt layout ---
#pragma unroll
    for (int nn = 0; nn < 4; ++nn) {
      const short* vrow = Vp + (size_t)(nn * 16 + fr) * 4096 + kt;
      const s16x8 vf0 = *(const s16x8*)(vrow + fg * 8);
      const s16x8 vf1 = *(const s16x8*)(vrow + 32 + fg * 8);
      acc[nn] = __builtin_amdgcn_mfma_f32_16x16x32_bf16(pf0, vf0, acc[nn], 0, 0, 0);
      acc[nn] = __builtin_amdgcn_mfma_f32_16x16x32_bf16(pf1, vf1, acc[nn], 0, 0, 0);
    }
  }

  // --- final fr-reduction of lrow ---
#pragma unroll
  for (int d = 1; d < 16; d <<= 1)
#pragma unroll
    for (int j = 0; j < 4; ++j) lrow[j] += __shfl_xor(lrow[j], d);

  // --- merge the two k-halves through LDS (overlay on P_lds) ---
  float* accb = (float*)P_lds;            // [4][16][64] f32 = 16 KB
  float* mlb  = accb + 4 * 16 * 64;       // [4][16][2]  f32
  __syncthreads();                        // all waves done with P_lds
  if (ks == 1) {
#pragma unroll
    for (int nn = 0; nn < 4; ++nn)
#pragma unroll
      for (int j = 0; j < 4; ++j)
        accb[(wq * 16 + fg * 4 + j) * 64 + nn * 16 + fr] = acc[nn][j];
    if (fr == 0) {
#pragma unroll
      for (int j = 0; j < 4; ++j) {
        mlb[(wq * 16 + fg * 4 + j) * 2]     = mrow[j];
        mlb[(wq * 16 + fg * 4 + j) * 2 + 1] = lrow[j];
      }
    }
  }
  __syncthreads();
  if (ks == 0) {
    float* outp = Out + (size_t)(b * 2048 + q0) * 1024 + h * 64;
#pragma unroll
    for (int j = 0; j < 4; ++j) {
      const float m2 = mlb[(wq * 16 + fg * 4 + j) * 2];
      const float l2 = mlb[(wq * 16 + fg * 4 + j) * 2 + 1];
      const float M  = fmaxf(mrow[j], m2);
      const float a1 = __expf(mrow[j] - M);
      const float a2 = __expf(m2 - M);
      const float inv = 1.0f / (lrow[j] * a1 + l2 * a2);
#pragma unroll
      for (int nn = 0; nn < 4; ++nn) {
        const float o = (acc[nn][j] * a1 +
                         accb[(wq * 16 + fg * 4 + j) * 64 + nn * 16 + fr] * a2) * inv;
        outp[(size_t)(fg * 4 + j) * 1024 + nn * 16 + fr] = o;
      }
    }
  }
}

// ---------------------------------------------------------------------------
extern "C" void kernel_launch(void* const* d_in, const int* in_sizes, int n_in,
                              void* d_out, int out_size, void* d_ws, size_t ws_size,
                              hipStream_t stream)
{
  const float* x   = (const float*)d_in[0];
  const float* Wq  = (const float*)d_in[1];
  const float* Wk  = (const float*)d_in[2];
  const float* Wv  = (const float*)d_in[3];
  const float* W1  = (const float*)d_in[4];
  const float* b1  = (const float*)d_in[5];
  const float* W2  = (const float*)d_in[6];
  const float* b2  = (const float*)d_in[7];
  const float* g1  = (const float*)d_in[8];
  const float* be1 = (const float*)d_in[9];
  const float* g2  = (const float*)d_in[10];
  const float* be2 = (const float*)d_in[11];
  float* out = (float*)d_out;

  const int M = 4096, D = 1024, DF = 4096;

  // workspace layout (lifetime-overlapped), total ~86 MB
  bf16* Wqk_t = (bf16*)d_ws;                        // [2048][1024]
  bf16* Wv_t  = Wqk_t + (size_t)2048 * 1024;        // [1024][1024]
  bf16* W1t   = Wv_t + (size_t)1024 * 1024;         // [4096][1024]
  bf16* W2t   = W1t + (size_t)4096 * 1024;          // [1024][4096]
  bf16* big   = W2t + (size_t)4096 * 1024;          // 16M elems = 32MB
  bf16* QK    = big;                                // [4096][2048] (dead after attn)
  bf16* Vt    = big + (size_t)8 * 1024 * 1024;      // [1024][4096] (dead after attn)
  bf16* hbuf  = big;                                // [4096][4096] (FFN1 out)
  char* p2    = (char*)(big + (size_t)16 * 1024 * 1024);
  bf16* xnorm = (bf16*)p2;                          // [4096][1024] (dead after gemms)
  float* attnO = (float*)p2;                        // [4096][1024] f32 (reuses xnorm)
  char* p3    = p2 + (size_t)M * D * sizeof(float);
  bf16* xres  = (bf16*)p3;                          // [4096][1024]
  bf16* xnorm2 = xres + (size_t)M * D;              // [4096][1024]

  // 1. weight transpose+convert
  transpose_cvt<<<dim3(32, 32), 256, 0, stream>>>(Wq, Wqk_t, D, D);
  transpose_cvt<<<dim3(32, 32), 256, 0, stream>>>(Wk, Wqk_t + (size_t)D * D, D, D);
  transpose_cvt<<<dim3(32, 32), 256, 0, stream>>>(Wv, Wv_t, D, D);
  transpose_cvt<<<dim3(128, 32), 256, 0, stream>>>(W1, W1t, D, DF);
  transpose_cvt<<<dim3(32, 128), 256, 0, stream>>>(W2, W2t, DF, D);
  // 2. LN1
  ln_bf16<<<M, 256, 0, stream>>>(x, g1, be1, xnorm);
  // 3. QK projection (fused Wq|Wk), row-major [4096][2048]
  gemm_bt<0><<<(M / 128) * (2048 / 128), 256, 0, stream>>>(
      xnorm, Wqk_t, QK, nullptr, nullptr, M, 2048, D);
  // 4. V projection directly transposed: Vt[d][s] = sum_k Wv_t[d][k]*xnorm[s][k]
  gemm_bt<0><<<(D / 128) * (M / 128), 256, 0, stream>>>(
      Wv_t, xnorm, Vt, nullptr, nullptr, D, M, D);
  // 5. attention (8 waves: 4 q-sub-tiles x 2 k-halves, merged in-block)
  attn_fwd<<<dim3(32, 32), 512, 0, stream>>>(QK, Vt, attnO);
  // 6. residual + LN2
  add_ln_bf16<<<M, 256, 0, stream>>>(attnO, x, g2, be2, xres, xnorm2);
  // 7. FFN1 (bias + relu fused)
  gemm_bt<1><<<(M / 128) * (DF / 128), 256, 0, stream>>>(
      xres, W1t, hbuf, b1, nullptr, M, DF, D);
  // 8. FFN2 (bias + x_norm2 add fused) -> f32 out
  gemm_bt<2><<<(M / 128) * (D / 128), 256, 0, stream>>>(
      hbuf, W2t, out, b2, xnorm2, M, D, DF);
}

// Round 4
// 301.722 us; speedup vs baseline: 1.7898x; 1.7898x over previous
//
#include <hip/hip_runtime.h>
#include <hip/hip_bf16.h>
#include <stdint.h>

typedef __hip_bfloat16 bf16;
typedef __attribute__((ext_vector_type(4))) float f32x4;
typedef __attribute__((ext_vector_type(8))) short s16x8;
typedef __attribute__((ext_vector_type(4))) short s16x4;

#define DEV static __device__ __forceinline__

DEV short f2bf(float f) {
  bf16 h = __float2bfloat16(f);
  short s;
  __builtin_memcpy(&s, &h, 2);
  return s;
}
DEV float bf2f(short s) {
  bf16 h;
  __builtin_memcpy(&h, &s, 2);
  return __bfloat162float(h);
}

// ------------- transpose + f32->bf16 convert: W[K][N] -> Wt[N][K] ----------
__global__ __launch_bounds__(256) void transpose_cvt(
    const float* __restrict__ W, bf16* __restrict__ Wt, int K, int N)
{
  __shared__ float tile[32][33];
  const int n0 = blockIdx.x << 5;
  const int k0 = blockIdx.y << 5;
  const int tx = threadIdx.x & 31, ty = threadIdx.x >> 5;
#pragma unroll
  for (int i = 0; i < 4; ++i)
    tile[ty + i * 8][tx] = W[(size_t)(k0 + ty + i * 8) * N + n0 + tx];
  __syncthreads();
#pragma unroll
  for (int i = 0; i < 4; ++i)
    Wt[(size_t)(n0 + ty + i * 8) * K + k0 + tx] = __float2bfloat16(tile[tx][ty + i * 8]);
}

// ------------- layernorm (f32 in, bf16 out), D = 1024 ---------------------
__global__ __launch_bounds__(256) void ln_bf16(
    const float* __restrict__ x, const float* __restrict__ g,
    const float* __restrict__ be, bf16* __restrict__ out)
{
  const int t = threadIdx.x;
  const size_t row = blockIdx.x;
  const float4 v = ((const float4*)(x + row * 1024))[t];
  float s = v.x + v.y + v.z + v.w;
  float ss = v.x * v.x + v.y * v.y + v.z * v.z + v.w * v.w;
#pragma unroll
  for (int off = 32; off > 0; off >>= 1) {
    s += __shfl_down(s, off);
    ss += __shfl_down(ss, off);
  }
  __shared__ float sh[8];
  const int wave = t >> 6, lane = t & 63;
  if (!lane) { sh[wave] = s; sh[4 + wave] = ss; }
  __syncthreads();
  s = sh[0] + sh[1] + sh[2] + sh[3];
  ss = sh[4] + sh[5] + sh[6] + sh[7];
  const float mean = s * (1.f / 1024.f);
  const float rstd = rsqrtf(ss * (1.f / 1024.f) - mean * mean + 1e-5f);
  const float4 gv = ((const float4*)g)[t];
  const float4 bv = ((const float4*)be)[t];
  s16x4 o;
  o[0] = f2bf((v.x - mean) * rstd * gv.x + bv.x);
  o[1] = f2bf((v.y - mean) * rstd * gv.y + bv.y);
  o[2] = f2bf((v.z - mean) * rstd * gv.z + bv.z);
  o[3] = f2bf((v.w - mean) * rstd * gv.w + bv.w);
  ((s16x4*)(out + row * 1024))[t] = o;
}

// ------------- residual add + layernorm ------------------------------------
__global__ __launch_bounds__(256) void add_ln_bf16(
    const float* __restrict__ a, const float* __restrict__ x,
    const float* __restrict__ g, const float* __restrict__ be,
    bf16* __restrict__ xres, bf16* __restrict__ xnorm)
{
  const int t = threadIdx.x;
  const size_t row = blockIdx.x;
  const float4 av = ((const float4*)(a + row * 1024))[t];
  const float4 xv = ((const float4*)(x + row * 1024))[t];
  float4 v;
  v.x = av.x + xv.x; v.y = av.y + xv.y; v.z = av.z + xv.z; v.w = av.w + xv.w;
  float s = v.x + v.y + v.z + v.w;
  float ss = v.x * v.x + v.y * v.y + v.z * v.z + v.w * v.w;
#pragma unroll
  for (int off = 32; off > 0; off >>= 1) {
    s += __shfl_down(s, off);
    ss += __shfl_down(ss, off);
  }
  __shared__ float sh[8];
  const int wave = t >> 6, lane = t & 63;
  if (!lane) { sh[wave] = s; sh[4 + wave] = ss; }
  __syncthreads();
  s = sh[0] + sh[1] + sh[2] + sh[3];
  ss = sh[4] + sh[5] + sh[6] + sh[7];
  const float mean = s * (1.f / 1024.f);
  const float rstd = rsqrtf(ss * (1.f / 1024.f) - mean * mean + 1e-5f);
  const float4 gv = ((const float4*)g)[t];
  const float4 bv = ((const float4*)be)[t];
  s16x4 r, o;
  r[0] = f2bf(v.x); r[1] = f2bf(v.y); r[2] = f2bf(v.z); r[3] = f2bf(v.w);
  o[0] = f2bf((v.x - mean) * rstd * gv.x + bv.x);
  o[1] = f2bf((v.y - mean) * rstd * gv.y + bv.y);
  o[2] = f2bf((v.z - mean) * rstd * gv.z + bv.z);
  o[3] = f2bf((v.w - mean) * rstd * gv.w + bv.w);
  ((s16x4*)(xres + row * 1024))[t] = r;
  ((s16x4*)(xnorm + row * 1024))[t] = o;
}

// ------------- GEMM: C[M][N] = A[M][K] @ Bt[N][K]^T, bf16 MFMA -------------
// EPI 0: C bf16 plain. EPI 1: bf16 relu(C + bias). EPI 2: f32 C + bias + add.
template <int EPI>
__global__ __launch_bounds__(256) void gemm_bt(
    const bf16* __restrict__ A, const bf16* __restrict__ Bt,
    void* __restrict__ C, const float* __restrict__ bias,
    const bf16* __restrict__ add_bf16, int M, int N, int K)
{
  __shared__ bf16 sA[128 * 32];
  __shared__ bf16 sB[128 * 32];
  const int tid = threadIdx.x;
  const int wave = tid >> 6, lane = tid & 63;
  const int fr = lane & 15, fg = lane >> 4;
  const int wr = wave >> 1, wc = wave & 1;
  const int nbx = N >> 7;
  const int brow = (blockIdx.x / nbx) << 7;
  const int bcol = (blockIdx.x % nbx) << 7;

  f32x4 acc[4][4] = {};

  const int c0 = wave * 64 + lane;   // staging chunk (16B) index, round 0
  const int c1 = c0 + 256;           // round 1
  const size_t ga0 = (size_t)(brow + (c0 >> 2)) * K + (c0 & 3) * 8;
  const size_t ga1 = (size_t)(brow + (c1 >> 2)) * K + (c1 & 3) * 8;
  const size_t gb0 = (size_t)(bcol + (c0 >> 2)) * K + (c0 & 3) * 8;
  const size_t gb1 = (size_t)(bcol + (c1 >> 2)) * K + (c1 & 3) * 8;
  bf16* sA0 = sA + (size_t)(wave * 64) * 8;
  bf16* sA1 = sA0 + 256 * 8;
  bf16* sB0 = sB + (size_t)(wave * 64) * 8;
  bf16* sB1 = sB0 + 256 * 8;

  for (int kt = 0; kt < K; kt += 32) {
    __builtin_amdgcn_global_load_lds(
        (const __attribute__((address_space(1))) uint32_t*)(A + ga0 + kt),
        (__attribute__((address_space(3))) uint32_t*)sA0, 16, 0, 0);
    __builtin_amdgcn_global_load_lds(
        (const __attribute__((address_space(1))) uint32_t*)(A + ga1 + kt),
        (__attribute__((address_space(3))) uint32_t*)sA1, 16, 0, 0);
    __builtin_amdgcn_global_load_lds(
        (const __attribute__((address_space(1))) uint32_t*)(Bt + gb0 + kt),
        (__attribute__((address_space(3))) uint32_t*)sB0, 16, 0, 0);
    __builtin_amdgcn_global_load_lds(
        (const __attribute__((address_space(1))) uint32_t*)(Bt + gb1 + kt),
        (__attribute__((address_space(3))) uint32_t*)sB1, 16, 0, 0);
    __syncthreads();

    s16x8 af[4], bfr[4];
#pragma unroll
    for (int m = 0; m < 4; ++m)
      af[m] = *(const s16x8*)(sA + ((wr * 64 + m * 16 + fr) * 32 + fg * 8));
#pragma unroll
    for (int n = 0; n < 4; ++n)
      bfr[n] = *(const s16x8*)(sB + ((wc * 64 + n * 16 + fr) * 32 + fg * 8));
#pragma unroll
    for (int m = 0; m < 4; ++m)
#pragma unroll
      for (int n = 0; n < 4; ++n)
        acc[m][n] = __builtin_amdgcn_mfma_f32_16x16x32_bf16(af[m], bfr[n], acc[m][n], 0, 0, 0);
    __syncthreads();
  }

  const int crow = brow + wr * 64;
  const int ccol = bcol + wc * 64;
#pragma unroll
  for (int m = 0; m < 4; ++m) {
#pragma unroll
    for (int n = 0; n < 4; ++n) {
      const int col = ccol + n * 16 + fr;
#pragma unroll
      for (int j = 0; j < 4; ++j) {
        const int row = crow + m * 16 + fg * 4 + j;
        float v = acc[m][n][j];
        if (EPI == 0) {
          ((bf16*)C)[(size_t)row * N + col] = __float2bfloat16(v);
        } else if (EPI == 1) {
          v += bias[col];
          v = fmaxf(v, 0.f);
          ((bf16*)C)[(size_t)row * N + col] = __float2bfloat16(v);
        } else {
          float a;
          {
            bf16 hb = add_bf16[(size_t)row * N + col];
            a = __bfloat162float(hb);
          }
          ((float*)C)[(size_t)row * N + col] = v + bias[col] + a;
        }
      }
    }
  }
}

// ------------- flash attention v4 ------------------------------------------
// QK [4096][2048] bf16 (Q cols 0..1023, K cols 1024..2047), Vt [1024][4096] bf16
// (row = h*64+d, col = b*2048+s).  Out [4096][1024] f32.
// grid (16 q-tiles of 128, 32 bh), 512 threads = 8 waves, each wave owns 16
// q-rows, ALL waves share the k-range. Per 64-k tile, K (64x64) and V (64x64)
// are staged once into LDS via global_load_lds (1 K-chunk + 1 V-chunk per
// wave), XOR-swizzled via pre-swizzled GLOBAL source (rule: linear LDS dest +
// inverse-swz source + swz read). 2-phase pipeline: stage(t+1) issued before
// compute(t); counted vmcnt + raw s_barrier (no full drain).
__global__ __launch_bounds__(512, 4) void attn_fwd(
    const bf16* __restrict__ QK, const bf16* __restrict__ Vt,
    float* __restrict__ Out)
{
  const int LDK = 2048;
  const int qt = blockIdx.x;
  const int bh = blockIdx.y;
  const int b = bh >> 4, h = bh & 15;
  const int tid = threadIdx.x;
  const int wave = tid >> 6, lane = tid & 63;
  const int fr = lane & 15, fg = lane >> 4;
  const int f7 = fr & 7;

  const short* base = (const short*)QK + (size_t)b * 2048 * LDK;
  const short* Qp = base + h * 64;
  const short* Kp = base + 1024 + h * 64;
  const short* Vp = (const short*)Vt + (size_t)h * 64 * 4096 + b * 2048;
  const int q0 = qt * 128 + wave * 16;

  // LDS: K tile [64 k][64 d] and V tile [64 d][64 k], both row=128B,
  // 16B-chunk index XOR-swizzled by (row&7). Double buffered.
  __shared__ short Kbuf[2][64 * 64];
  __shared__ short Vbuf[2][64 * 64];
  __shared__ short P_lds[8][16 * 72];
  short* Pw = P_lds[wave];

  // staging source addresses (per lane): chunk s = wave, row = 8s + (l>>3),
  // logical 16B-chunk = (l&7) ^ (l>>3)   [inverse of the read-side swizzle]
  const int rsub = lane >> 3;              // 0..7
  const int clog = (lane & 7) ^ rsub;      // source chunk (shorts: *8)
  const short* Ksrc = Kp + (size_t)(8 * wave + rsub) * LDK + clog * 8;
  const short* Vsrc = Vp + (size_t)(8 * wave + rsub) * 4096 + clog * 8;

  // Q fragment, pre-scaled by 1/sqrt(64) = 0.125 (exact in bf16)
  s16x8 qf0 = *(const s16x8*)(Qp + (size_t)(q0 + fr) * LDK + fg * 8);
  s16x8 qf1 = *(const s16x8*)(Qp + (size_t)(q0 + fr) * LDK + 32 + fg * 8);
#pragma unroll
  for (int i = 0; i < 8; ++i) {
    qf0[i] = f2bf(bf2f(qf0[i]) * 0.125f);
    qf1[i] = f2bf(bf2f(qf1[i]) * 0.125f);
  }

  f32x4 acc[4] = {};
  f32x4 mrow = {-1e30f, -1e30f, -1e30f, -1e30f};
  f32x4 lrow = {};   // per-lane partial; fr-reduced once at the end

#define STAGE(bi, kt)                                                          \
  do {                                                                         \
    __builtin_amdgcn_global_load_lds(                                          \
        (const __attribute__((address_space(1))) uint32_t*)(Ksrc + (size_t)(kt) * LDK), \
        (__attribute__((address_space(3))) uint32_t*)(&Kbuf[bi][wave * 512]),  \
        16, 0, 0);                                                             \
    __builtin_amdgcn_global_load_lds(                                          \
        (const __attribute__((address_space(1))) uint32_t*)(Vsrc + (kt)),      \
        (__attribute__((address_space(3))) uint32_t*)(&Vbuf[bi][wave * 512]),  \
        16, 0, 0);                                                             \
  } while (0)

  int cur = 0;
  STAGE(0, 0);

  for (int kt = 0; kt < 2048; kt += 64) {
    // ---- phase A: prefetch next tile, then wait for current tile ----
    if (kt + 64 < 2048) {
      STAGE(cur ^ 1, kt + 64);
      asm volatile("s_waitcnt vmcnt(2)" ::: "memory");
    } else {
      asm volatile("s_waitcnt vmcnt(0)" ::: "memory");
    }
    __builtin_amdgcn_s_barrier();          // all waves' chunks landed
    __builtin_amdgcn_sched_barrier(0);

    const short* Kb = Kbuf[cur];
    const short* Vb = Vbuf[cur];

    // ---- QK^T: e[t] = 16x16 tile (q rows x k cols), swizzled LDS reads ----
    f32x4 e[4];
#pragma unroll
    for (int t = 0; t < 4; ++t) {
      const int ro = (t * 16 + fr) * 64;
      const s16x8 k0 = *(const s16x8*)(Kb + ro + ((fg ^ f7) << 3));
      const s16x8 k1 = *(const s16x8*)(Kb + ro + (((4 + fg) ^ f7) << 3));
      f32x4 z = {};
      z = __builtin_amdgcn_mfma_f32_16x16x32_bf16(qf0, k0, z, 0, 0, 0);
      z = __builtin_amdgcn_mfma_f32_16x16x32_bf16(qf1, k1, z, 0, 0, 0);
      e[t] = z;
    }

    // ---- per-lane defer-max: cross-lane tree + rescale only on growth > 8 ----
    f32x4 lmx;
#pragma unroll
    for (int j = 0; j < 4; ++j)
      lmx[j] = fmaxf(fmaxf(e[0][j], e[1][j]), fmaxf(e[2][j], e[3][j]));
    const bool need = (lmx[0] > mrow[0] + 8.f) | (lmx[1] > mrow[1] + 8.f) |
                      (lmx[2] > mrow[2] + 8.f) | (lmx[3] > mrow[3] + 8.f);
    if (__any(need)) {
      f32x4 mx = lmx;
#pragma unroll
      for (int d = 1; d < 16; d <<= 1)
#pragma unroll
        for (int j = 0; j < 4; ++j) mx[j] = fmaxf(mx[j], __shfl_xor(mx[j], d));
#pragma unroll
      for (int j = 0; j < 4; ++j) {
        const float mn = fmaxf(mrow[j], mx[j]);
        const float al = __expf(mrow[j] - mn);
        lrow[j] *= al;
        mrow[j] = mn;
#pragma unroll
        for (int nn = 0; nn < 4; ++nn) acc[nn][j] *= al;
      }
    }

    // ---- exp in place + per-lane partial row-sum ----
#pragma unroll
    for (int j = 0; j < 4; ++j) {
#pragma unroll
      for (int t = 0; t < 4; ++t) e[t][j] = __expf(e[t][j] - mrow[j]);
      lrow[j] += (e[0][j] + e[1][j]) + (e[2][j] + e[3][j]);
    }

    // ---- P transpose through wave-private LDS (in-order DS, no barrier) ----
#pragma unroll
    for (int t = 0; t < 4; ++t)
#pragma unroll
      for (int j = 0; j < 4; ++j)
        Pw[(fg * 4 + j) * 72 + t * 16 + fr] = f2bf(e[t][j]);
    const s16x8 pf0 = *(const s16x8*)(Pw + fr * 72 + fg * 8);
    const s16x8 pf1 = *(const s16x8*)(Pw + fr * 72 + 32 + fg * 8);

    // ---- PV from swizzled V tile ----
#pragma unroll
    for (int nn = 0; nn < 4; ++nn) {
      const int ro = (nn * 16 + fr) * 64;
      const s16x8 vf0 = *(const s16x8*)(Vb + ro + ((fg ^ f7) << 3));
      const s16x8 vf1 = *(const s16x8*)(Vb + ro + (((4 + fg) ^ f7) << 3));
      acc[nn] = __builtin_amdgcn_mfma_f32_16x16x32_bf16(pf0, vf0, acc[nn], 0, 0, 0);
      acc[nn] = __builtin_amdgcn_mfma_f32_16x16x32_bf16(pf1, vf1, acc[nn], 0, 0, 0);
    }

    // ---- end barrier: everyone done reading buf[cur]; next iter's STAGE
    //      may overwrite it only after this point ----
    __builtin_amdgcn_s_barrier();
    __builtin_amdgcn_sched_barrier(0);
    cur ^= 1;
  }
#undef STAGE

  // ---- final fr-reduction of lrow, normalize + store ----
#pragma unroll
  for (int d = 1; d < 16; d <<= 1)
#pragma unroll
    for (int j = 0; j < 4; ++j) lrow[j] += __shfl_xor(lrow[j], d);
  f32x4 inv;
#pragma unroll
  for (int j = 0; j < 4; ++j) inv[j] = 1.0f / lrow[j];
  float* outp = Out + (size_t)(b * 2048 + q0) * 1024 + h * 64;
#pragma unroll
  for (int nn = 0; nn < 4; ++nn)
#pragma unroll
    for (int j = 0; j < 4; ++j)
      outp[(size_t)(fg * 4 + j) * 1024 + nn * 16 + fr] = acc[nn][j] * inv[j];
}

// ---------------------------------------------------------------------------
extern "C" void kernel_launch(void* const* d_in, const int* in_sizes, int n_in,
                              void* d_out, int out_size, void* d_ws, size_t ws_size,
                              hipStream_t stream)
{
  const float* x   = (const float*)d_in[0];
  const float* Wq  = (const float*)d_in[1];
  const float* Wk  = (const float*)d_in[2];
  const float* Wv  = (const float*)d_in[3];
  const float* W1  = (const float*)d_in[4];
  const float* b1  = (const float*)d_in[5];
  const float* W2  = (const float*)d_in[6];
  const float* b2  = (const float*)d_in[7];
  const float* g1  = (const float*)d_in[8];
  const float* be1 = (const float*)d_in[9];
  const float* g2  = (const float*)d_in[10];
  const float* be2 = (const float*)d_in[11];
  float* out = (float*)d_out;

  const int M = 4096, D = 1024, DF = 4096;

  // workspace layout (lifetime-overlapped), total ~86 MB
  bf16* Wqk_t = (bf16*)d_ws;                        // [2048][1024]
  bf16* Wv_t  = Wqk_t + (size_t)2048 * 1024;        // [1024][1024]
  bf16* W1t   = Wv_t + (size_t)1024 * 1024;         // [4096][1024]
  bf16* W2t   = W1t + (size_t)4096 * 1024;          // [1024][4096]
  bf16* big   = W2t + (size_t)4096 * 1024;          // 16M elems = 32MB
  bf16* QK    = big;                                // [4096][2048] (dead after attn)
  bf16* Vt    = big + (size_t)8 * 1024 * 1024;      // [1024][4096] (dead after attn)
  bf16* hbuf  = big;                                // [4096][4096] (FFN1 out)
  char* p2    = (char*)(big + (size_t)16 * 1024 * 1024);
  bf16* xnorm = (bf16*)p2;                          // [4096][1024] (dead after gemms)
  float* attnO = (float*)p2;                        // [4096][1024] f32 (reuses xnorm)
  char* p3    = p2 + (size_t)M * D * sizeof(float);
  bf16* xres  = (bf16*)p3;                          // [4096][1024]
  bf16* xnorm2 = xres + (size_t)M * D;              // [4096][1024]

  // 1. weight transpose+convert
  transpose_cvt<<<dim3(32, 32), 256, 0, stream>>>(Wq, Wqk_t, D, D);
  transpose_cvt<<<dim3(32, 32), 256, 0, stream>>>(Wk, Wqk_t + (size_t)D * D, D, D);
  transpose_cvt<<<dim3(32, 32), 256, 0, stream>>>(Wv, Wv_t, D, D);
  transpose_cvt<<<dim3(128, 32), 256, 0, stream>>>(W1, W1t, D, DF);
  transpose_cvt<<<dim3(32, 128), 256, 0, stream>>>(W2, W2t, DF, D);
  // 2. LN1
  ln_bf16<<<M, 256, 0, stream>>>(x, g1, be1, xnorm);
  // 3. QK projection (fused Wq|Wk), row-major [4096][2048]
  gemm_bt<0><<<(M / 128) * (2048 / 128), 256, 0, stream>>>(
      xnorm, Wqk_t, QK, nullptr, nullptr, M, 2048, D);
  // 4. V projection directly transposed: Vt[d][s] = sum_k Wv_t[d][k]*xnorm[s][k]
  gemm_bt<0><<<(D / 128) * (M / 128), 256, 0, stream>>>(
      Wv_t, xnorm, Vt, nullptr, nullptr, D, M, D);
  // 5. attention (8 waves sharing LDS-staged K/V tiles, 2-phase pipeline)
  attn_fwd<<<dim3(16, 32), 512, 0, stream>>>(QK, Vt, attnO);
  // 6. residual + LN2
  add_ln_bf16<<<M, 256, 0, stream>>>(attnO, x, g2, be2, xres, xnorm2);
  // 7. FFN1 (bias + relu fused)
  gemm_bt<1><<<(M / 128) * (DF / 128), 256, 0, stream>>>(
      xres, W1t, hbuf, b1, nullptr, M, DF, D);
  // 8. FFN2 (bias + x_norm2 add fused) -> f32 out
  gemm_bt<2><<<(M / 128) * (D / 128), 256, 0, stream>>>(
      hbuf, W2t, out, b2, xnorm2, M, D, DF);
}